// Round 1
// baseline (1200.031 us; speedup 1.0000x reference)
//
#include <hip/hip_runtime.h>
#include <math.h>

#define HQ   12
#define DH   64
#define NSEQ 1024
#define BB   4
#define DIMM 768
#define RR   8
#define BHD  (BB*HQ)      // 48
#define MROWS (BB*NSEQ)   // 4096
#define OUT_ELEMS (BB*NSEQ*DIMM)  // 3145728

// ---------------------------------------------------------------------------
// GEMM: C[m, i] = sum_k A[m,k] * W[i,k]   (M=4096, N=768, K=768)
// MODE 0: A plain row-major [M x 768]; C scattered to (b,h,n,d) layout
// MODE 1: A in (b,h,n,d) layout (attn out); C plain [M x 768] + bias
// Tiles: BM=BN=64, BK=16; 256 threads; 4x4 micro-tile per thread.
// LDS stored K-major with row stride 68 floats (16B-aligned ds_read_b128,
// conflict-free/2-way reads).
// ---------------------------------------------------------------------------
template<int MODE>
__global__ __launch_bounds__(256)
void gemm_kernel(const float* __restrict__ A, const float* __restrict__ W,
                 const float* __restrict__ bias, float* __restrict__ C)
{
    __shared__ float As[16][68];
    __shared__ float Bs[16][68];
    const int tid = threadIdx.x;
    const int blockM = blockIdx.y * 64;
    const int blockN = blockIdx.x * 64;   // == h*64 for MODE 0
    const int lrow = tid >> 2;            // 0..63
    const int lc4  = (tid & 3) * 4;       // 0,4,8,12
    const int tx = tid & 15, ty = tid >> 4;

    float acc[4][4] = {};

    for (int kt = 0; kt < 768; kt += 16) {
        float4 a4, b4;
        {
            const int m  = blockM + lrow;
            const int kg = kt + lc4;
            if (MODE == 0) {
                a4 = *(const float4*)(A + m*768 + kg);
            } else {
                const int b = m >> 10, n = m & 1023;
                const int h = kg >> 6, dh = kg & 63;
                a4 = *(const float4*)(A + ((((b*HQ + h) << 10) + n) << 6) + dh);
            }
            b4 = *(const float4*)(W + (blockN + lrow)*768 + kt + lc4);
        }
        __syncthreads();   // previous tile fully consumed
        As[lc4 + 0][lrow] = a4.x;  As[lc4 + 1][lrow] = a4.y;
        As[lc4 + 2][lrow] = a4.z;  As[lc4 + 3][lrow] = a4.w;
        Bs[lc4 + 0][lrow] = b4.x;  Bs[lc4 + 1][lrow] = b4.y;
        Bs[lc4 + 2][lrow] = b4.z;  Bs[lc4 + 3][lrow] = b4.w;
        __syncthreads();
        #pragma unroll
        for (int kk = 0; kk < 16; ++kk) {
            const float4 av = *(const float4*)&As[kk][ty*4];
            const float4 bv = *(const float4*)&Bs[kk][tx*4];
            const float a_[4] = {av.x, av.y, av.z, av.w};
            const float b_[4] = {bv.x, bv.y, bv.z, bv.w};
            #pragma unroll
            for (int i = 0; i < 4; ++i)
                #pragma unroll
                for (int j = 0; j < 4; ++j)
                    acc[i][j] += a_[i] * b_[j];
        }
    }

    if (MODE == 0) {
        const int h = blockIdx.x;         // BN==64 => one head per block col
        #pragma unroll
        for (int i = 0; i < 4; ++i) {
            const int m = blockM + ty*4 + i;
            const int b = m >> 10, n = m & 1023;
            float4 v4 = make_float4(acc[i][0], acc[i][1], acc[i][2], acc[i][3]);
            *(float4*)(C + ((((b*HQ + h) << 10) + n) << 6) + tx*4) = v4;
        }
    } else {
        const int gi = blockN + tx*4;
        const float4 bs4 = *(const float4*)(bias + gi);
        #pragma unroll
        for (int i = 0; i < 4; ++i) {
            const int m = blockM + ty*4 + i;
            float4 v4 = make_float4(acc[i][0] + bs4.x, acc[i][1] + bs4.y,
                                    acc[i][2] + bs4.z, acc[i][3] + bs4.w);
            *(float4*)(C + m*768 + gi) = v4;
        }
    }
}

// ---------------------------------------------------------------------------
// SPD projection: per (bh,n) row of q/k (64 floats), compute
//   l[r] = log(softplus(q . sw[r] + sb[r]) + 1e-6 + 1e-8),  r=0..7
// plus per-row squared norm. 8 lanes per row, 32 rows per 256-thread block.
// ---------------------------------------------------------------------------
__global__ __launch_bounds__(256)
void spd_kernel(const float* __restrict__ qk, const float* __restrict__ sw,
                const float* __restrict__ sb, float* __restrict__ lout,
                float* __restrict__ nout)
{
    const int tid = threadIdx.x;
    const int r = tid & 7;
    const int row = blockIdx.x * 32 + (tid >> 3);
    const float* qp = qk + row*64;
    const float* wp = sw + r*64;
    float acc = sb[r];
    #pragma unroll
    for (int d = 0; d < 64; ++d) acc += qp[d] * wp[d];
    // softplus (stable)
    float sp = (acc > 0.f) ? (acc + log1pf(__expf(-acc))) : log1pf(__expf(acc));
    float l = __logf(sp + 1e-6f + 1e-8f);
    lout[row*8 + r] = l;
    float s = l * l;
    s += __shfl_xor(s, 1);
    s += __shfl_xor(s, 2);
    s += __shfl_xor(s, 4);
    if (r == 0) nout[row] = s;
}

// ---------------------------------------------------------------------------
// Attention: per (bh, query) — one wave per query, 4 queries per block.
//   d2(i,j) = |lq_i|^2 + |lk_j|^2 - 2 lq_i.lk_j ; dist=sqrt(max(d2,1e-12))
//   w = exp(-dist/8);  out = (sum_j w_j v_j) / (sum_j w_j)
// Keys staged in 64-wide LDS chunks; weights broadcast via __shfl.
// ---------------------------------------------------------------------------
__global__ __launch_bounds__(256)
void attn_kernel(const float* __restrict__ lq, const float* __restrict__ lk,
                 const float* __restrict__ nq, const float* __restrict__ nk,
                 const float* __restrict__ v, float* __restrict__ out)
{
    __shared__ float lk_s[64*9];     // stride-9 pad: conflict-free
    __shared__ float nk_s[64];
    __shared__ float v_s[64*64];
    const int tid  = threadIdx.x;
    const int lane = tid & 63;
    const int wid  = tid >> 6;
    const int bh   = blockIdx.y;
    const int qi   = blockIdx.x * 4 + wid;
    const int qrow = bh*NSEQ + qi;

    float lqr[8];
    #pragma unroll
    for (int r = 0; r < 8; ++r) lqr[r] = lq[qrow*8 + r];
    const float nqv = nq[qrow];

    float o = 0.f, wsum = 0.f;

    for (int c = 0; c < NSEQ; c += 64) {
        __syncthreads();   // protect previous chunk's LDS from overwrite
        for (int t = tid; t < 512; t += 256) {
            const int j = t >> 3, r = t & 7;
            lk_s[j*9 + r] = lk[(bh*NSEQ + c + j)*8 + r];
        }
        if (tid < 64) nk_s[tid] = nk[bh*NSEQ + c + tid];
        #pragma unroll
        for (int u = 0; u < 4; ++u) {
            const int idx = tid + u*256;            // float4 index 0..1023
            const int j = idx >> 4, d0 = (idx & 15) * 4;
            *(float4*)&v_s[j*64 + d0] =
                *(const float4*)(v + ((bh*NSEQ + c + j) << 6) + d0);
        }
        __syncthreads();

        // this lane's key weight
        float dot = 0.f;
        #pragma unroll
        for (int r = 0; r < 8; ++r) dot += lqr[r] * lk_s[lane*9 + r];
        const float d2 = nqv + nk_s[lane] - 2.f*dot;
        const float dist = sqrtf(fmaxf(d2, 1e-12f));
        const float w = __expf(dist * -0.125f);

        #pragma unroll 16
        for (int jj = 0; jj < 64; ++jj) {
            const float wj = __shfl(w, jj);
            o += wj * v_s[jj*64 + lane];
            wsum += wj;
        }
    }
    out[(qrow << 6) + lane] = o / wsum;
}

// ---------------------------------------------------------------------------
// KL reduction: 0.5 * sum over 4 (mu, ls) pairs of exp(2ls)+mu^2-1-2ls.
// 589824 = 9 * 65536 elements per pair; double accumulation.
// ---------------------------------------------------------------------------
__global__ __launch_bounds__(256)
void kl_partial_kernel(const float* __restrict__ mu0, const float* __restrict__ ls0,
                       const float* __restrict__ mu1, const float* __restrict__ ls1,
                       const float* __restrict__ mu2, const float* __restrict__ ls2,
                       const float* __restrict__ mu3, const float* __restrict__ ls3,
                       double* __restrict__ partials)
{
    const int tid = threadIdx.x;
    double acc = 0.0;
    for (int idx = blockIdx.x*256 + tid; idx < 589824; idx += 256*256) {
        float m, l;
        m = mu0[idx]; l = ls0[idx]; acc += (double)(expf(2.f*l) + m*m - 1.f - 2.f*l);
        m = mu1[idx]; l = ls1[idx]; acc += (double)(expf(2.f*l) + m*m - 1.f - 2.f*l);
        m = mu2[idx]; l = ls2[idx]; acc += (double)(expf(2.f*l) + m*m - 1.f - 2.f*l);
        m = mu3[idx]; l = ls3[idx]; acc += (double)(expf(2.f*l) + m*m - 1.f - 2.f*l);
    }
    __shared__ double sd[256];
    sd[tid] = acc;
    __syncthreads();
    for (int s = 128; s > 0; s >>= 1) {
        if (tid < s) sd[tid] += sd[tid + s];
        __syncthreads();
    }
    if (tid == 0) partials[blockIdx.x] = sd[0];
}

__global__ __launch_bounds__(256)
void kl_final_kernel(const double* __restrict__ partials, float* __restrict__ out_kl)
{
    const int tid = threadIdx.x;
    __shared__ double sd[256];
    sd[tid] = partials[tid];
    __syncthreads();
    for (int s = 128; s > 0; s >>= 1) {
        if (tid < s) sd[tid] += sd[tid + s];
        __syncthreads();
    }
    if (tid == 0) out_kl[0] = (float)(0.5 * sd[0]);
}

// ---------------------------------------------------------------------------
extern "C" void kernel_launch(void* const* d_in, const int* in_sizes, int n_in,
                              void* d_out, int out_size, void* d_ws, size_t ws_size,
                              hipStream_t stream)
{
    const float* x     = (const float*)d_in[0];
    const float* wq    = (const float*)d_in[1];
    const float* wq_ls = (const float*)d_in[2];
    const float* wk    = (const float*)d_in[3];
    const float* wk_ls = (const float*)d_in[4];
    const float* wv    = (const float*)d_in[5];
    const float* wv_ls = (const float*)d_in[6];
    const float* wo    = (const float*)d_in[7];
    const float* wo_ls = (const float*)d_in[8];
    const float* wo_b  = (const float*)d_in[9];
    const float* sq_w  = (const float*)d_in[10];
    const float* sq_b  = (const float*)d_in[11];
    const float* sk_w  = (const float*)d_in[12];
    const float* sk_b  = (const float*)d_in[13];
    float* out = (float*)d_out;

    float* ws   = (float*)d_ws;
    float* bufA = ws;                       // 3145728 floats (q then k)
    float* bufV = ws + 3145728;             // 3145728
    float* bufO = ws + 2*3145728;           // 3145728
    float* lqb  = ws + 3*3145728;           // 393216
    float* lkb  = lqb + 393216;             // 393216
    float* nqb  = lkb + 393216;             // 49152
    float* nkb  = nqb + 49152;              // 49152
    double* partials = (double*)(nkb + 49152);  // 256 doubles, 8B-aligned

    const dim3 b256(256);
    const dim3 gGemm(12, 64);

    gemm_kernel<0><<<gGemm, b256, 0, stream>>>(x, wq, nullptr, bufA);
    spd_kernel<<<1536, b256, 0, stream>>>(bufA, sq_w, sq_b, lqb, nqb);
    gemm_kernel<0><<<gGemm, b256, 0, stream>>>(x, wk, nullptr, bufA);
    spd_kernel<<<1536, b256, 0, stream>>>(bufA, sk_w, sk_b, lkb, nkb);
    gemm_kernel<0><<<gGemm, b256, 0, stream>>>(x, wv, nullptr, bufV);
    attn_kernel<<<dim3(256, BHD), b256, 0, stream>>>(lqb, lkb, nqb, nkb, bufV, bufO);
    gemm_kernel<1><<<gGemm, b256, 0, stream>>>(bufO, wo, wo_b, out);
    kl_partial_kernel<<<256, b256, 0, stream>>>(wq, wq_ls, wk, wk_ls, wv, wv_ls,
                                                wo, wo_ls, partials);
    kl_final_kernel<<<1, b256, 0, stream>>>(partials, out + OUT_ELEMS);
}

// Round 2
// 503.696 us; speedup vs baseline: 2.3825x; 2.3825x over previous
//
#include <hip/hip_runtime.h>
#include <math.h>

#define HQ   12
#define DH   64
#define NSEQ 1024
#define BB   4
#define DIMM 768
#define RR   8
#define BHD  (BB*HQ)      // 48
#define MROWS (BB*NSEQ)   // 4096
#define OUT_ELEMS (BB*NSEQ*DIMM)  // 3145728

typedef short bf16x8 __attribute__((ext_vector_type(8)));
typedef float f32x4  __attribute__((ext_vector_type(4)));

__device__ __forceinline__ unsigned short f2bf(float f) {
    union { float f; unsigned u; } x; x.f = f;
    return (unsigned short)((x.u + 0x7fffu + ((x.u >> 16) & 1u)) >> 16);
}

// ---------------------------------------------------------------------------
// GEMM: C[m, i] = sum_k A[m,k] * W[i,k]   (M=4096, N=768, K=768)
// MODE 0: A plain row-major; C scattered to (b,h,n,d) fp32   (Q, K proj)
// MODE 1: A in (b,h,n,d) (attn out); C plain [M x 768] + bias (O proj)
// MODE 2: A plain row-major; C = Vt bf16 in (b,h,d,n) layout  (V proj)
// ---------------------------------------------------------------------------
template<int MODE>
__global__ __launch_bounds__(256)
void gemm_kernel(const float* __restrict__ A, const float* __restrict__ W,
                 const float* __restrict__ bias, float* __restrict__ C)
{
    __shared__ float As[16][68];
    __shared__ float Bs[16][68];
    const int tid = threadIdx.x;
    const int blockM = blockIdx.y * 64;
    const int blockN = blockIdx.x * 64;   // == h*64 for MODE 0/2
    const int lrow = tid >> 2;            // 0..63
    const int lc4  = (tid & 3) * 4;       // 0,4,8,12
    const int tx = tid & 15, ty = tid >> 4;

    float acc[4][4] = {};

    for (int kt = 0; kt < 768; kt += 16) {
        float4 a4, b4;
        {
            const int m  = blockM + lrow;
            const int kg = kt + lc4;
            if (MODE == 1) {
                const int b = m >> 10, n = m & 1023;
                const int h = kg >> 6, dh = kg & 63;
                a4 = *(const float4*)(A + ((((b*HQ + h) << 10) + n) << 6) + dh);
            } else {
                a4 = *(const float4*)(A + m*768 + kg);
            }
            b4 = *(const float4*)(W + (blockN + lrow)*768 + kt + lc4);
        }
        __syncthreads();   // previous tile fully consumed
        As[lc4 + 0][lrow] = a4.x;  As[lc4 + 1][lrow] = a4.y;
        As[lc4 + 2][lrow] = a4.z;  As[lc4 + 3][lrow] = a4.w;
        Bs[lc4 + 0][lrow] = b4.x;  Bs[lc4 + 1][lrow] = b4.y;
        Bs[lc4 + 2][lrow] = b4.z;  Bs[lc4 + 3][lrow] = b4.w;
        __syncthreads();
        #pragma unroll
        for (int kk = 0; kk < 16; ++kk) {
            const float4 av = *(const float4*)&As[kk][ty*4];
            const float4 bv = *(const float4*)&Bs[kk][tx*4];
            const float a_[4] = {av.x, av.y, av.z, av.w};
            const float b_[4] = {bv.x, bv.y, bv.z, bv.w};
            #pragma unroll
            for (int i = 0; i < 4; ++i)
                #pragma unroll
                for (int j = 0; j < 4; ++j)
                    acc[i][j] += a_[i] * b_[j];
        }
    }

    if (MODE == 0) {
        const int h = blockIdx.x;
        #pragma unroll
        for (int i = 0; i < 4; ++i) {
            const int m = blockM + ty*4 + i;
            const int b = m >> 10, n = m & 1023;
            float4 v4 = make_float4(acc[i][0], acc[i][1], acc[i][2], acc[i][3]);
            *(float4*)(C + ((((b*HQ + h) << 10) + n) << 6) + tx*4) = v4;
        }
    } else if (MODE == 1) {
        const int gi = blockN + tx*4;
        const float4 bs4 = *(const float4*)(bias + gi);
        #pragma unroll
        for (int i = 0; i < 4; ++i) {
            const int m = blockM + ty*4 + i;
            float4 v4 = make_float4(acc[i][0] + bs4.x, acc[i][1] + bs4.y,
                                    acc[i][2] + bs4.z, acc[i][3] + bs4.w);
            *(float4*)(C + m*768 + gi) = v4;
        }
    } else {  // MODE 2: Vt bf16 (bh, d, n)
        unsigned short* Ct = (unsigned short*)C;
        const int b  = blockM >> 10;
        const int n0 = (blockM & 1023) + ty*4;
        const int bh = b*HQ + blockIdx.x;
        #pragma unroll
        for (int j = 0; j < 4; ++j) {
            const int d = tx*4 + j;
            unsigned lo = (unsigned)f2bf(acc[0][j]) | ((unsigned)f2bf(acc[1][j]) << 16);
            unsigned hi = (unsigned)f2bf(acc[2][j]) | ((unsigned)f2bf(acc[3][j]) << 16);
            *(uint2*)(Ct + (((bh << 6) + d) << 10) + n0) = make_uint2(lo, hi);
        }
    }
}

// ---------------------------------------------------------------------------
// SPD projection (unchanged)
// ---------------------------------------------------------------------------
__global__ __launch_bounds__(256)
void spd_kernel(const float* __restrict__ qk, const float* __restrict__ sw,
                const float* __restrict__ sb, float* __restrict__ lout,
                float* __restrict__ nout)
{
    const int tid = threadIdx.x;
    const int r = tid & 7;
    const int row = blockIdx.x * 32 + (tid >> 3);
    const float* qp = qk + row*64;
    const float* wp = sw + r*64;
    float acc = sb[r];
    #pragma unroll
    for (int d = 0; d < 64; ++d) acc += qp[d] * wp[d];
    float sp = (acc > 0.f) ? (acc + log1pf(__expf(-acc))) : log1pf(__expf(acc));
    float l = __logf(sp + 1e-6f + 1e-8f);
    lout[row*8 + r] = l;
    float s = l * l;
    s += __shfl_xor(s, 1);
    s += __shfl_xor(s, 2);
    s += __shfl_xor(s, 4);
    if (r == 0) nout[row] = s;
}

// ---------------------------------------------------------------------------
// Attention v2: flash-style, MFMA P·V.
// Grid (16, 48): block = 64 queries of one bh; 4 waves, wave = 16q x 64d slab.
// Per 64-key chunk: lane(q=lane&15, kg=lane>>4) computes 16 weights,
// packs bf16 -> w_s (A-layout rows); V staged pre-transposed bf16 (vt) ->
// B-frags contiguous; 8x mfma_f32_16x16x32_bf16 per wave per chunk.
// ---------------------------------------------------------------------------
__global__ __launch_bounds__(256)
void attn_kernel(const float* __restrict__ lq, const float* __restrict__ lk,
                 const float* __restrict__ nq, const float* __restrict__ nk,
                 const unsigned short* __restrict__ vt, float* __restrict__ out)
{
    __shared__ float lk_s[64*12];          // stride 12: 16B-aligned, 2-way max
    __shared__ float nk_s[64];
    __shared__ unsigned short vt_s[64*72]; // stride 72 bf16 = 144B (16B mult), 2-way
    __shared__ unsigned short w_s[64*72];

    const int tid  = threadIdx.x;
    const int lane = tid & 63;
    const int wid  = tid >> 6;
    const int bh   = blockIdx.y;
    const int qt   = blockIdx.x;
    const int qr   = lane & 15;
    const int quad = lane >> 4;
    const int q0   = qt*64 + wid*16;
    const int qrow = (bh << 10) + q0 + qr;

    float lqr[8];
    {
        const float4 a = *(const float4*)(lq + qrow*8);
        const float4 b = *(const float4*)(lq + qrow*8 + 4);
        lqr[0]=a.x; lqr[1]=a.y; lqr[2]=a.z; lqr[3]=a.w;
        lqr[4]=b.x; lqr[5]=b.y; lqr[6]=b.z; lqr[7]=b.w;
    }
    const float nqv = nq[qrow];

    f32x4 acc[4] = {};
    float wsum_acc = 0.f;

    const unsigned short* vtg = vt + (bh << 16);  // bh*64*1024

    for (int c = 0; c < NSEQ; c += 64) {
        __syncthreads();   // previous chunk fully consumed
        if (tid < 128) {
            const int k = tid >> 1, half = tid & 1;
            *(float4*)&lk_s[k*12 + half*4] =
                *(const float4*)(lk + (((bh << 10) + c + k) << 3) + half*4);
        } else if (tid < 192) {
            nk_s[tid - 128] = nk[(bh << 10) + c + tid - 128];
        }
        {
            const int d = tid >> 2, p = tid & 3;
            const unsigned short* src = vtg + (d << 10) + c + (p << 4);
            *(uint4*)&vt_s[d*72 + (p << 4)]     = *(const uint4*)(src);
            *(uint4*)&vt_s[d*72 + (p << 4) + 8] = *(const uint4*)(src + 8);
        }
        __syncthreads();

        // --- weights: this lane covers q=qr, k = quad*16 + 0..15 ---
        float wsum_c = 0.f;
        unsigned wpk[8];
        #pragma unroll
        for (int kk = 0; kk < 16; kk += 2) {
            float wpair[2];
            #pragma unroll
            for (int t = 0; t < 2; ++t) {
                const int k = quad*16 + kk + t;
                const float4 f0 = *(const float4*)&lk_s[k*12];
                const float4 f1 = *(const float4*)&lk_s[k*12 + 4];
                float dot = lqr[0]*f0.x + lqr[1]*f0.y + lqr[2]*f0.z + lqr[3]*f0.w
                          + lqr[4]*f1.x + lqr[5]*f1.y + lqr[6]*f1.z + lqr[7]*f1.w;
                float d2 = nqv + nk_s[k] - 2.f*dot;
                float w = __expf(-0.125f * sqrtf(fmaxf(d2, 1e-12f)));
                wpair[t] = w; wsum_c += w;
            }
            wpk[kk >> 1] = (unsigned)f2bf(wpair[0]) | ((unsigned)f2bf(wpair[1]) << 16);
        }
        {
            unsigned short* wrow = &w_s[(wid*16 + qr)*72 + quad*16];
            *(uint4*)wrow       = make_uint4(wpk[0], wpk[1], wpk[2], wpk[3]);
            *(uint4*)(wrow + 8) = make_uint4(wpk[4], wpk[5], wpk[6], wpk[7]);
        }
        wsum_c += __shfl_xor(wsum_c, 16);
        wsum_c += __shfl_xor(wsum_c, 32);
        wsum_acc += wsum_c;

        // --- P·V via MFMA (w_s rows are wave-private; no barrier needed) ---
        #pragma unroll
        for (int s = 0; s < 2; ++s) {
            const bf16x8 af = *(const bf16x8*)&w_s[(wid*16 + qr)*72 + s*32 + quad*8];
            #pragma unroll
            for (int jb = 0; jb < 4; ++jb) {
                const bf16x8 bfr = *(const bf16x8*)&vt_s[(jb*16 + qr)*72 + s*32 + quad*8];
                acc[jb] = __builtin_amdgcn_mfma_f32_16x16x32_bf16(af, bfr, acc[jb], 0, 0, 0);
            }
        }
    }

    // epilogue: normalize by wsum, store (b,h,n,d) fp32
    #pragma unroll
    for (int jb = 0; jb < 4; ++jb) {
        #pragma unroll
        for (int r = 0; r < 4; ++r) {
            const int row = quad*4 + r;                 // q row within slab
            const float ws = __shfl(wsum_acc, row);     // lane 'row' holds q=row
            const int qgl = q0 + row;
            const int d = jb*16 + qr;
            out[(((bh << 10) + qgl) << 6) + d] = acc[jb][r] / ws;
        }
    }
}

// ---------------------------------------------------------------------------
// KL reduction (unchanged)
// ---------------------------------------------------------------------------
__global__ __launch_bounds__(256)
void kl_partial_kernel(const float* __restrict__ mu0, const float* __restrict__ ls0,
                       const float* __restrict__ mu1, const float* __restrict__ ls1,
                       const float* __restrict__ mu2, const float* __restrict__ ls2,
                       const float* __restrict__ mu3, const float* __restrict__ ls3,
                       double* __restrict__ partials)
{
    const int tid = threadIdx.x;
    double acc = 0.0;
    for (int idx = blockIdx.x*256 + tid; idx < 589824; idx += 256*256) {
        float m, l;
        m = mu0[idx]; l = ls0[idx]; acc += (double)(expf(2.f*l) + m*m - 1.f - 2.f*l);
        m = mu1[idx]; l = ls1[idx]; acc += (double)(expf(2.f*l) + m*m - 1.f - 2.f*l);
        m = mu2[idx]; l = ls2[idx]; acc += (double)(expf(2.f*l) + m*m - 1.f - 2.f*l);
        m = mu3[idx]; l = ls3[idx]; acc += (double)(expf(2.f*l) + m*m - 1.f - 2.f*l);
    }
    __shared__ double sd[256];
    sd[tid] = acc;
    __syncthreads();
    for (int s = 128; s > 0; s >>= 1) {
        if (tid < s) sd[tid] += sd[tid + s];
        __syncthreads();
    }
    if (tid == 0) partials[blockIdx.x] = sd[0];
}

__global__ __launch_bounds__(256)
void kl_final_kernel(const double* __restrict__ partials, float* __restrict__ out_kl)
{
    const int tid = threadIdx.x;
    __shared__ double sd[256];
    sd[tid] = partials[tid];
    __syncthreads();
    for (int s = 128; s > 0; s >>= 1) {
        if (tid < s) sd[tid] += sd[tid + s];
        __syncthreads();
    }
    if (tid == 0) out_kl[0] = (float)(0.5 * sd[0]);
}

// ---------------------------------------------------------------------------
extern "C" void kernel_launch(void* const* d_in, const int* in_sizes, int n_in,
                              void* d_out, int out_size, void* d_ws, size_t ws_size,
                              hipStream_t stream)
{
    const float* x     = (const float*)d_in[0];
    const float* wq    = (const float*)d_in[1];
    const float* wk    = (const float*)d_in[3];
    const float* wv    = (const float*)d_in[5];
    const float* wo    = (const float*)d_in[7];
    const float* wq_ls = (const float*)d_in[2];
    const float* wk_ls = (const float*)d_in[4];
    const float* wv_ls = (const float*)d_in[6];
    const float* wo_ls = (const float*)d_in[8];
    const float* wo_b  = (const float*)d_in[9];
    const float* sq_w  = (const float*)d_in[10];
    const float* sq_b  = (const float*)d_in[11];
    const float* sk_w  = (const float*)d_in[12];
    const float* sk_b  = (const float*)d_in[13];
    float* out = (float*)d_out;

    float* ws   = (float*)d_ws;
    float* bufA = ws;                         // 3145728 floats (q then k)
    float* bufO = ws + 3145728;               // 3145728 floats
    unsigned short* vtb = (unsigned short*)(ws + 2*3145728);  // 3145728 bf16 = 1572864 floats
    float* lqb  = ws + 2*3145728 + 1572864;   // 393216
    float* lkb  = lqb + 393216;               // 393216
    float* nqb  = lkb + 393216;               // 49152
    float* nkb  = nqb + 49152;                // 49152
    double* partials = (double*)(nkb + 49152);

    const dim3 b256(256);
    const dim3 gGemm(12, 64);

    gemm_kernel<0><<<gGemm, b256, 0, stream>>>(x, wq, nullptr, bufA);
    spd_kernel<<<1536, b256, 0, stream>>>(bufA, sq_w, sq_b, lqb, nqb);
    gemm_kernel<0><<<gGemm, b256, 0, stream>>>(x, wk, nullptr, bufA);
    spd_kernel<<<1536, b256, 0, stream>>>(bufA, sk_w, sk_b, lkb, nkb);
    gemm_kernel<2><<<gGemm, b256, 0, stream>>>(x, wv, nullptr, (float*)vtb);
    attn_kernel<<<dim3(16, BHD), b256, 0, stream>>>(lqb, lkb, nqb, nkb, vtb, bufO);
    gemm_kernel<1><<<gGemm, b256, 0, stream>>>(bufO, wo, wo_b, out);
    kl_partial_kernel<<<256, b256, 0, stream>>>(wq, wq_ls, wk, wk_ls, wv, wv_ls,
                                                wo, wo_ls, partials);
    kl_final_kernel<<<1, b256, 0, stream>>>(partials, out + OUT_ELEMS);
}

// Round 3
// 279.748 us; speedup vs baseline: 4.2897x; 1.8005x over previous
//
#include <hip/hip_runtime.h>
#include <math.h>

#define HQ   12
#define DH   64
#define NSEQ 1024
#define BB   4
#define DIMM 768
#define RR   8
#define BHD  (BB*HQ)      // 48
#define MROWS (BB*NSEQ)   // 4096
#define OUT_ELEMS (BB*NSEQ*DIMM)  // 3145728

typedef short bf16x8 __attribute__((ext_vector_type(8)));
typedef float f32x4  __attribute__((ext_vector_type(4)));

__device__ __forceinline__ unsigned short f2bf(float f) {
    union { float f; unsigned u; } x; x.f = f;
    return (unsigned short)((x.u + 0x7fffu + ((x.u >> 16) & 1u)) >> 16);
}

#define AS_GLOBAL(p) ((const __attribute__((address_space(1))) void*)(p))
#define AS_LDS(p)    ((__attribute__((address_space(3))) void*)(p))

// ---------------------------------------------------------------------------
// fp32 -> bf16 conversion: x (seg 0), wq/wk/wv -> fused wf (segs 1-3), wo (4)
// ---------------------------------------------------------------------------
__global__ __launch_bounds__(256)
void convert_kernel(const float* __restrict__ x,  const float* __restrict__ wq,
                    const float* __restrict__ wk, const float* __restrict__ wv,
                    const float* __restrict__ wo, unsigned short* __restrict__ xb,
                    unsigned short* __restrict__ wf, unsigned short* __restrict__ wob)
{
    const int seg = blockIdx.y;
    const float* src; unsigned short* dst; int n4;
    if      (seg == 0) { src = x;  dst = xb;            n4 = 786432; }
    else if (seg == 1) { src = wq; dst = wf;            n4 = 147456; }
    else if (seg == 2) { src = wk; dst = wf + 589824;   n4 = 147456; }
    else if (seg == 3) { src = wv; dst = wf + 1179648;  n4 = 147456; }
    else               { src = wo; dst = wob;           n4 = 147456; }
    for (int i = blockIdx.x*256 + threadIdx.x; i < n4; i += gridDim.x*256) {
        float4 v = ((const float4*)src)[i];
        unsigned lo = (unsigned)f2bf(v.x) | ((unsigned)f2bf(v.y) << 16);
        unsigned hi = (unsigned)f2bf(v.z) | ((unsigned)f2bf(v.w) << 16);
        ((uint2*)dst)[i] = make_uint2(lo, hi);
    }
}

// ---------------------------------------------------------------------------
// MFMA GEMM, m97 structure: 128x128 tile, BK=32, 4 waves x (4x4 16x16x32).
// MODE 0 (QKV fused, grid 18x32):
//   bx<6: Q -> qb fp32 (b,h,n,d); 6<=bx<12: K -> kb fp32 (b,h,n,d)
//   bx>=12: V with A/B swapped (acc = C^T) -> vt bf16 (bh,d,n)
// MODE 1 (O-proj, grid 6x32): A = attn bf16 [4096][768], out fp32 + bias
// ---------------------------------------------------------------------------
template<int MODE>
__global__ __launch_bounds__(256)
void mfma_gemm(const unsigned short* __restrict__ X,
               const unsigned short* __restrict__ Wf,
               const float* __restrict__ bias,
               float* __restrict__ qb, float* __restrict__ kb,
               unsigned short* __restrict__ vt, float* __restrict__ outp)
{
    __shared__ unsigned short As[128*32];   // 8 KB, unpadded (global_load_lds)
    __shared__ unsigned short Bs[128*32];
    const int tid  = threadIdx.x;
    const int lane = tid & 63;
    const int qr   = lane & 15, quad = lane >> 4;
    const int wid  = tid >> 6;
    const int w_m  = wid >> 1, w_n = wid & 1;
    const int bx = blockIdx.x, by = blockIdx.y;

    const bool vmode = (MODE == 0) && (bx >= 12);
    const unsigned short* Abase = vmode ? (Wf + bx*128*768) : (X + by*128*768);
    const unsigned short* Bbase = vmode ? (X + by*128*768) : (Wf + bx*128*768);

    const int row0 = tid >> 2;          // 0..63
    const int segk = (tid & 3) * 8;     // k offset 0/8/16/24

    f32x4 acc[4][4] = {};

    for (int kt = 0; kt < 768; kt += 32) {
        __syncthreads();   // previous tile fully consumed
        const unsigned short* ga = Abase + row0*768 + kt + segk;
        const unsigned short* gb = Bbase + row0*768 + kt + segk;
        __builtin_amdgcn_global_load_lds(AS_GLOBAL(ga),          AS_LDS(&As[tid*8]),        16, 0, 0);
        __builtin_amdgcn_global_load_lds(AS_GLOBAL(ga + 64*768), AS_LDS(&As[2048 + tid*8]), 16, 0, 0);
        __builtin_amdgcn_global_load_lds(AS_GLOBAL(gb),          AS_LDS(&Bs[tid*8]),        16, 0, 0);
        __builtin_amdgcn_global_load_lds(AS_GLOBAL(gb + 64*768), AS_LDS(&Bs[2048 + tid*8]), 16, 0, 0);
        __syncthreads();   // implicit vmcnt(0) drain

        bf16x8 a[4], b[4];
        #pragma unroll
        for (int mi = 0; mi < 4; ++mi)
            a[mi] = *(const bf16x8*)&As[(w_m*64 + mi*16 + qr)*32 + quad*8];
        #pragma unroll
        for (int ni = 0; ni < 4; ++ni)
            b[ni] = *(const bf16x8*)&Bs[(w_n*64 + ni*16 + qr)*32 + quad*8];
        #pragma unroll
        for (int mi = 0; mi < 4; ++mi)
            #pragma unroll
            for (int ni = 0; ni < 4; ++ni)
                acc[mi][ni] = __builtin_amdgcn_mfma_f32_16x16x32_bf16(a[mi], b[ni], acc[mi][ni], 0, 0, 0);
    }

    if (MODE == 1) {
        #pragma unroll
        for (int ni = 0; ni < 4; ++ni) {
            const int i = bx*128 + w_n*64 + ni*16 + qr;
            const float bs = bias[i];
            #pragma unroll
            for (int mi = 0; mi < 4; ++mi) {
                const int m0 = by*128 + w_m*64 + mi*16 + quad*4;
                #pragma unroll
                for (int r = 0; r < 4; ++r)
                    outp[(m0 + r)*768 + i] = acc[mi][ni][r] + bs;
            }
        }
    } else if (!vmode) {
        float* dst; int chb;
        if (bx < 6) { dst = qb; chb = bx*128; } else { dst = kb; chb = bx*128 - 768; }
        #pragma unroll
        for (int ni = 0; ni < 4; ++ni) {
            const int i = chb + w_n*64 + ni*16 + qr;
            const int h = i >> 6, d = i & 63;
            #pragma unroll
            for (int mi = 0; mi < 4; ++mi) {
                const int m0 = by*128 + w_m*64 + mi*16 + quad*4;
                #pragma unroll
                for (int r = 0; r < 4; ++r) {
                    const int m = m0 + r;
                    const int b = m >> 10, n = m & 1023;
                    dst[((((b*HQ + h) << 10) + n) << 6) + d] = acc[mi][ni][r];
                }
            }
        }
    } else {
        const int chb = bx*128 - 1536;
        #pragma unroll
        for (int mi = 0; mi < 4; ++mi) {
            #pragma unroll
            for (int r = 0; r < 4; ++r) {
                const int i = chb + w_m*64 + mi*16 + quad*4 + r;   // V channel
                const int h = i >> 6, d = i & 63;
                #pragma unroll
                for (int ni = 0; ni < 4; ++ni) {
                    const int mcol = by*128 + w_n*64 + ni*16 + qr; // seq index
                    const int b = mcol >> 10, n = mcol & 1023;
                    vt[((((b*HQ + h) << 6) + d) << 10) + n] = f2bf(acc[mi][ni][r]);
                }
            }
        }
    }
}

// ---------------------------------------------------------------------------
// SPD projection (unchanged)
// ---------------------------------------------------------------------------
__global__ __launch_bounds__(256)
void spd_kernel(const float* __restrict__ qk, const float* __restrict__ sw,
                const float* __restrict__ sb, float* __restrict__ lout,
                float* __restrict__ nout)
{
    const int tid = threadIdx.x;
    const int r = tid & 7;
    const int row = blockIdx.x * 32 + (tid >> 3);
    const float* qp = qk + row*64;
    const float* wp = sw + r*64;
    float acc = sb[r];
    #pragma unroll
    for (int d = 0; d < 64; ++d) acc += qp[d] * wp[d];
    float sp = (acc > 0.f) ? (acc + log1pf(__expf(-acc))) : log1pf(__expf(acc));
    float l = __logf(sp + 1e-6f + 1e-8f);
    lout[row*8 + r] = l;
    float s = l * l;
    s += __shfl_xor(s, 1);
    s += __shfl_xor(s, 2);
    s += __shfl_xor(s, 4);
    if (r == 0) nout[row] = s;
}

// ---------------------------------------------------------------------------
// Attention: flash-style, MFMA P·V; epilogue now emits bf16 [4096][768]
// ---------------------------------------------------------------------------
__global__ __launch_bounds__(256)
void attn_kernel(const float* __restrict__ lq, const float* __restrict__ lk,
                 const float* __restrict__ nq, const float* __restrict__ nk,
                 const unsigned short* __restrict__ vt, unsigned short* __restrict__ out)
{
    __shared__ float lk_s[64*12];
    __shared__ float nk_s[64];
    __shared__ unsigned short vt_s[64*72];
    __shared__ unsigned short w_s[64*72];

    const int tid  = threadIdx.x;
    const int lane = tid & 63;
    const int wid  = tid >> 6;
    const int bh   = blockIdx.y;
    const int qt   = blockIdx.x;
    const int qr   = lane & 15;
    const int quad = lane >> 4;
    const int q0   = qt*64 + wid*16;
    const int qrow = (bh << 10) + q0 + qr;
    const int bb   = bh / HQ;
    const int hh   = bh - bb*HQ;

    float lqr[8];
    {
        const float4 a = *(const float4*)(lq + qrow*8);
        const float4 b = *(const float4*)(lq + qrow*8 + 4);
        lqr[0]=a.x; lqr[1]=a.y; lqr[2]=a.z; lqr[3]=a.w;
        lqr[4]=b.x; lqr[5]=b.y; lqr[6]=b.z; lqr[7]=b.w;
    }
    const float nqv = nq[qrow];

    f32x4 acc[4] = {};
    float wsum_acc = 0.f;

    const unsigned short* vtg = vt + (bh << 16);

    for (int c = 0; c < NSEQ; c += 64) {
        __syncthreads();
        if (tid < 128) {
            const int k = tid >> 1, half = tid & 1;
            *(float4*)&lk_s[k*12 + half*4] =
                *(const float4*)(lk + (((bh << 10) + c + k) << 3) + half*4);
        } else if (tid < 192) {
            nk_s[tid - 128] = nk[(bh << 10) + c + tid - 128];
        }
        {
            const int d = tid >> 2, p = tid & 3;
            const unsigned short* src = vtg + (d << 10) + c + (p << 4);
            *(uint4*)&vt_s[d*72 + (p << 4)]     = *(const uint4*)(src);
            *(uint4*)&vt_s[d*72 + (p << 4) + 8] = *(const uint4*)(src + 8);
        }
        __syncthreads();

        float wsum_c = 0.f;
        unsigned wpk[8];
        #pragma unroll
        for (int kk = 0; kk < 16; kk += 2) {
            float wpair[2];
            #pragma unroll
            for (int t = 0; t < 2; ++t) {
                const int k = quad*16 + kk + t;
                const float4 f0 = *(const float4*)&lk_s[k*12];
                const float4 f1 = *(const float4*)&lk_s[k*12 + 4];
                float dot = lqr[0]*f0.x + lqr[1]*f0.y + lqr[2]*f0.z + lqr[3]*f0.w
                          + lqr[4]*f1.x + lqr[5]*f1.y + lqr[6]*f1.z + lqr[7]*f1.w;
                float d2 = nqv + nk_s[k] - 2.f*dot;
                float w = __expf(-0.125f * sqrtf(fmaxf(d2, 1e-12f)));
                wpair[t] = w; wsum_c += w;
            }
            wpk[kk >> 1] = (unsigned)f2bf(wpair[0]) | ((unsigned)f2bf(wpair[1]) << 16);
        }
        {
            unsigned short* wrow = &w_s[(wid*16 + qr)*72 + quad*16];
            *(uint4*)wrow       = make_uint4(wpk[0], wpk[1], wpk[2], wpk[3]);
            *(uint4*)(wrow + 8) = make_uint4(wpk[4], wpk[5], wpk[6], wpk[7]);
        }
        wsum_c += __shfl_xor(wsum_c, 16);
        wsum_c += __shfl_xor(wsum_c, 32);
        wsum_acc += wsum_c;

        #pragma unroll
        for (int s = 0; s < 2; ++s) {
            const bf16x8 af = *(const bf16x8*)&w_s[(wid*16 + qr)*72 + s*32 + quad*8];
            #pragma unroll
            for (int jb = 0; jb < 4; ++jb) {
                const bf16x8 bfr = *(const bf16x8*)&vt_s[(jb*16 + qr)*72 + s*32 + quad*8];
                acc[jb] = __builtin_amdgcn_mfma_f32_16x16x32_bf16(af, bfr, acc[jb], 0, 0, 0);
            }
        }
    }

    // epilogue: normalize, store bf16 [b*1024+n][h*64+d] for the O-proj GEMM
    #pragma unroll
    for (int jb = 0; jb < 4; ++jb) {
        #pragma unroll
        for (int r = 0; r < 4; ++r) {
            const int row = quad*4 + r;
            const float ws = __shfl(wsum_acc, row);
            const int qgl = q0 + row;
            const int d = jb*16 + qr;
            out[((bb << 10) + qgl)*768 + hh*64 + d] = f2bf(acc[jb][r] / ws);
        }
    }
}

// ---------------------------------------------------------------------------
// KL reduction (unchanged)
// ---------------------------------------------------------------------------
__global__ __launch_bounds__(256)
void kl_partial_kernel(const float* __restrict__ mu0, const float* __restrict__ ls0,
                       const float* __restrict__ mu1, const float* __restrict__ ls1,
                       const float* __restrict__ mu2, const float* __restrict__ ls2,
                       const float* __restrict__ mu3, const float* __restrict__ ls3,
                       double* __restrict__ partials)
{
    const int tid = threadIdx.x;
    double acc = 0.0;
    for (int idx = blockIdx.x*256 + tid; idx < 589824; idx += 256*256) {
        float m, l;
        m = mu0[idx]; l = ls0[idx]; acc += (double)(expf(2.f*l) + m*m - 1.f - 2.f*l);
        m = mu1[idx]; l = ls1[idx]; acc += (double)(expf(2.f*l) + m*m - 1.f - 2.f*l);
        m = mu2[idx]; l = ls2[idx]; acc += (double)(expf(2.f*l) + m*m - 1.f - 2.f*l);
        m = mu3[idx]; l = ls3[idx]; acc += (double)(expf(2.f*l) + m*m - 1.f - 2.f*l);
    }
    __shared__ double sd[256];
    sd[tid] = acc;
    __syncthreads();
    for (int s = 128; s > 0; s >>= 1) {
        if (tid < s) sd[tid] += sd[tid + s];
        __syncthreads();
    }
    if (tid == 0) partials[blockIdx.x] = sd[0];
}

__global__ __launch_bounds__(256)
void kl_final_kernel(const double* __restrict__ partials, float* __restrict__ out_kl)
{
    const int tid = threadIdx.x;
    __shared__ double sd[256];
    sd[tid] = partials[tid];
    __syncthreads();
    for (int s = 128; s > 0; s >>= 1) {
        if (tid < s) sd[tid] += sd[tid + s];
        __syncthreads();
    }
    if (tid == 0) out_kl[0] = (float)(0.5 * sd[0]);
}

// ---------------------------------------------------------------------------
extern "C" void kernel_launch(void* const* d_in, const int* in_sizes, int n_in,
                              void* d_out, int out_size, void* d_ws, size_t ws_size,
                              hipStream_t stream)
{
    const float* x     = (const float*)d_in[0];
    const float* wq    = (const float*)d_in[1];
    const float* wq_ls = (const float*)d_in[2];
    const float* wk    = (const float*)d_in[3];
    const float* wk_ls = (const float*)d_in[4];
    const float* wv    = (const float*)d_in[5];
    const float* wv_ls = (const float*)d_in[6];
    const float* wo    = (const float*)d_in[7];
    const float* wo_ls = (const float*)d_in[8];
    const float* wo_b  = (const float*)d_in[9];
    const float* sq_w  = (const float*)d_in[10];
    const float* sq_b  = (const float*)d_in[11];
    const float* sk_w  = (const float*)d_in[12];
    const float* sk_b  = (const float*)d_in[13];
    float* out = (float*)d_out;

    float* ws = (float*)d_ws;
    float* qb = ws;                                   // 3145728 f
    float* kb = ws + 3145728;                         // 3145728 f
    unsigned short* vt  = (unsigned short*)(ws + 6291456);   // 1572864 f
    unsigned short* xb  = (unsigned short*)(ws + 7864320);   // 1572864 f (re-used as attn bf16 out)
    unsigned short* wf  = (unsigned short*)(ws + 9437184);   // 884736 f
    unsigned short* wob = (unsigned short*)(ws + 10321920);  // 294912 f
    float* lqb = ws + 10616832;                       // 393216
    float* lkb = ws + 11010048;                       // 393216
    float* nqb = ws + 11403264;                       // 49152
    float* nkb = ws + 11452416;                       // 49152
    double* partials = (double*)(ws + 11501568);      // 256 doubles

    const dim3 b256(256);

    convert_kernel<<<dim3(1024, 5), b256, 0, stream>>>(x, wq, wk, wv, wo, xb, wf, wob);
    mfma_gemm<0><<<dim3(18, 32), b256, 0, stream>>>(xb, wf, nullptr, qb, kb, vt, nullptr);
    spd_kernel<<<1536, b256, 0, stream>>>(qb, sq_w, sq_b, lqb, nqb);
    spd_kernel<<<1536, b256, 0, stream>>>(kb, sk_w, sk_b, lkb, nkb);
    attn_kernel<<<dim3(16, BHD), b256, 0, stream>>>(lqb, lkb, nqb, nkb, vt, xb);
    mfma_gemm<1><<<dim3(6, 32), b256, 0, stream>>>(xb, wob, wo_b, nullptr, nullptr, nullptr, out);
    kl_partial_kernel<<<256, b256, 0, stream>>>(wq, wq_ls, wk, wk_ls, wv, wv_ls,
                                                wo, wo_ls, partials);
    kl_final_kernel<<<1, b256, 0, stream>>>(partials, out + OUT_ELEMS);
}

// Round 4
// 268.955 us; speedup vs baseline: 4.4618x; 1.0401x over previous
//
#include <hip/hip_runtime.h>
#include <math.h>

#define HQ   12
#define DH   64
#define NSEQ 1024
#define BB   4
#define DIMM 768
#define RR   8
#define BHD  (BB*HQ)      // 48
#define MROWS (BB*NSEQ)   // 4096
#define OUT_ELEMS (BB*NSEQ*DIMM)  // 3145728

typedef short bf16x8 __attribute__((ext_vector_type(8)));
typedef float f32x4  __attribute__((ext_vector_type(4)));

__device__ __forceinline__ unsigned short f2bf(float f) {
    union { float f; unsigned u; } x; x.f = f;
    return (unsigned short)((x.u + 0x7fffu + ((x.u >> 16) & 1u)) >> 16);
}
__device__ __forceinline__ float bf2f(unsigned short b) {
    union { unsigned u; float f; } x; x.u = ((unsigned)b) << 16;
    return x.f;
}

#define AS_GLOBAL(p) ((const __attribute__((address_space(1))) void*)(p))
#define AS_LDS(p)    ((__attribute__((address_space(3))) void*)(p))

// ---------------------------------------------------------------------------
// fp32 -> bf16 conversion: x (seg 0), wq/wk/wv -> fused wf (segs 1-3), wo (4)
// ---------------------------------------------------------------------------
__global__ __launch_bounds__(256)
void convert_kernel(const float* __restrict__ x,  const float* __restrict__ wq,
                    const float* __restrict__ wk, const float* __restrict__ wv,
                    const float* __restrict__ wo, unsigned short* __restrict__ xb,
                    unsigned short* __restrict__ wf, unsigned short* __restrict__ wob)
{
    const int seg = blockIdx.y;
    const float* src; unsigned short* dst; int n4;
    if      (seg == 0) { src = x;  dst = xb;            n4 = 786432; }
    else if (seg == 1) { src = wq; dst = wf;            n4 = 147456; }
    else if (seg == 2) { src = wk; dst = wf + 589824;   n4 = 147456; }
    else if (seg == 3) { src = wv; dst = wf + 1179648;  n4 = 147456; }
    else               { src = wo; dst = wob;           n4 = 147456; }
    for (int i = blockIdx.x*256 + threadIdx.x; i < n4; i += gridDim.x*256) {
        float4 v = ((const float4*)src)[i];
        unsigned lo = (unsigned)f2bf(v.x) | ((unsigned)f2bf(v.y) << 16);
        unsigned hi = (unsigned)f2bf(v.z) | ((unsigned)f2bf(v.w) << 16);
        ((uint2*)dst)[i] = make_uint2(lo, hi);
    }
}

// ---------------------------------------------------------------------------
// MFMA GEMM, m97 structure: 128x128 tile, BK=32, 4 waves x (4x4 16x16x32).
// MODE 0 (QKV fused, grid 18x32):
//   bx<6: Q -> qb fp32 (b,h,n,d); 6<=bx<12: K -> kb fp32 (b,h,n,d)
//   bx>=12: V with A/B swapped (acc = C^T) -> vt bf16 (bh,d,n)
// MODE 1 (O-proj, grid 6x32): A = attn bf16 [4096][768], out fp32 + bias
// ---------------------------------------------------------------------------
template<int MODE>
__global__ __launch_bounds__(256)
void mfma_gemm(const unsigned short* __restrict__ X,
               const unsigned short* __restrict__ Wf,
               const float* __restrict__ bias,
               float* __restrict__ qb, float* __restrict__ kb,
               unsigned short* __restrict__ vt, float* __restrict__ outp)
{
    __shared__ unsigned short As[128*32];   // 8 KB, unpadded (global_load_lds)
    __shared__ unsigned short Bs[128*32];
    const int tid  = threadIdx.x;
    const int lane = tid & 63;
    const int qr   = lane & 15, quad = lane >> 4;
    const int wid  = tid >> 6;
    const int w_m  = wid >> 1, w_n = wid & 1;
    const int bx = blockIdx.x, by = blockIdx.y;

    const bool vmode = (MODE == 0) && (bx >= 12);
    const unsigned short* Abase = vmode ? (Wf + bx*128*768) : (X + by*128*768);
    const unsigned short* Bbase = vmode ? (X + by*128*768) : (Wf + bx*128*768);

    const int row0 = tid >> 2;          // 0..63
    const int segk = (tid & 3) * 8;     // k offset 0/8/16/24

    f32x4 acc[4][4] = {};

    for (int kt = 0; kt < 768; kt += 32) {
        __syncthreads();   // previous tile fully consumed
        const unsigned short* ga = Abase + row0*768 + kt + segk;
        const unsigned short* gb = Bbase + row0*768 + kt + segk;
        __builtin_amdgcn_global_load_lds(AS_GLOBAL(ga),          AS_LDS(&As[tid*8]),        16, 0, 0);
        __builtin_amdgcn_global_load_lds(AS_GLOBAL(ga + 64*768), AS_LDS(&As[2048 + tid*8]), 16, 0, 0);
        __builtin_amdgcn_global_load_lds(AS_GLOBAL(gb),          AS_LDS(&Bs[tid*8]),        16, 0, 0);
        __builtin_amdgcn_global_load_lds(AS_GLOBAL(gb + 64*768), AS_LDS(&Bs[2048 + tid*8]), 16, 0, 0);
        __syncthreads();   // implicit vmcnt(0) drain

        bf16x8 a[4], b[4];
        #pragma unroll
        for (int mi = 0; mi < 4; ++mi)
            a[mi] = *(const bf16x8*)&As[(w_m*64 + mi*16 + qr)*32 + quad*8];
        #pragma unroll
        for (int ni = 0; ni < 4; ++ni)
            b[ni] = *(const bf16x8*)&Bs[(w_n*64 + ni*16 + qr)*32 + quad*8];
        #pragma unroll
        for (int mi = 0; mi < 4; ++mi)
            #pragma unroll
            for (int ni = 0; ni < 4; ++ni)
                acc[mi][ni] = __builtin_amdgcn_mfma_f32_16x16x32_bf16(a[mi], b[ni], acc[mi][ni], 0, 0, 0);
    }

    if (MODE == 1) {
        #pragma unroll
        for (int ni = 0; ni < 4; ++ni) {
            const int i = bx*128 + w_n*64 + ni*16 + qr;
            const float bs = bias[i];
            #pragma unroll
            for (int mi = 0; mi < 4; ++mi) {
                const int m0 = by*128 + w_m*64 + mi*16 + quad*4;
                #pragma unroll
                for (int r = 0; r < 4; ++r)
                    outp[(m0 + r)*768 + i] = acc[mi][ni][r] + bs;
            }
        }
    } else if (!vmode) {
        float* dst; int chb;
        if (bx < 6) { dst = qb; chb = bx*128; } else { dst = kb; chb = bx*128 - 768; }
        #pragma unroll
        for (int ni = 0; ni < 4; ++ni) {
            const int i = chb + w_n*64 + ni*16 + qr;
            const int h = i >> 6, d = i & 63;
            #pragma unroll
            for (int mi = 0; mi < 4; ++mi) {
                const int m0 = by*128 + w_m*64 + mi*16 + quad*4;
                #pragma unroll
                for (int r = 0; r < 4; ++r) {
                    const int m = m0 + r;
                    const int b = m >> 10, n = m & 1023;
                    dst[((((b*HQ + h) << 10) + n) << 6) + d] = acc[mi][ni][r];
                }
            }
        }
    } else {
        const int chb = bx*128 - 1536;
        #pragma unroll
        for (int mi = 0; mi < 4; ++mi) {
            #pragma unroll
            for (int r = 0; r < 4; ++r) {
                const int i = chb + w_m*64 + mi*16 + quad*4 + r;   // V channel
                const int h = i >> 6, d = i & 63;
                #pragma unroll
                for (int ni = 0; ni < 4; ++ni) {
                    const int mcol = by*128 + w_n*64 + ni*16 + qr; // seq index
                    const int b = mcol >> 10, n = mcol & 1023;
                    vt[((((b*HQ + h) << 6) + d) << 10) + n] = f2bf(acc[mi][ni][r]);
                }
            }
        }
    }
}

// ---------------------------------------------------------------------------
// SPD projection (q and k fused via blockIdx.y).
// Emits bf16 log-vectors + fp32 norms computed on the ROUNDED values so that
// d2 = nq + nk - 2*dot_bf16 stays consistent (>= ~0).
// ---------------------------------------------------------------------------
__global__ __launch_bounds__(256)
void spd_kernel(const float* __restrict__ qb, const float* __restrict__ kb,
                const float* __restrict__ sqw, const float* __restrict__ sqb,
                const float* __restrict__ skw, const float* __restrict__ skb,
                unsigned short* __restrict__ lqo, unsigned short* __restrict__ lko,
                float* __restrict__ nqo, float* __restrict__ nko)
{
    const int which = blockIdx.y;
    const float* src = which ? kb  : qb;
    const float* wp0 = which ? skw : sqw;
    const float* bp  = which ? skb : sqb;
    unsigned short* lo = which ? lko : lqo;
    float* no = which ? nko : nqo;

    const int tid = threadIdx.x;
    const int r = tid & 7;
    const int row = blockIdx.x * 32 + (tid >> 3);
    const float* qp = src + row*64;
    const float* wp = wp0 + r*64;
    float acc = bp[r];
    #pragma unroll
    for (int d = 0; d < 64; ++d) acc += qp[d] * wp[d];
    float sp = (acc > 0.f) ? (acc + log1pf(__expf(-acc))) : log1pf(__expf(acc));
    float l = __logf(sp + 1e-6f + 1e-8f);
    const unsigned short lb = f2bf(l);
    lo[row*8 + r] = lb;
    const float lr = bf2f(lb);
    float s = lr * lr;
    s += __shfl_xor(s, 1);
    s += __shfl_xor(s, 2);
    s += __shfl_xor(s, 4);
    if (r == 0) no[row] = s;
}

// ---------------------------------------------------------------------------
// Attention v3: both S (geodesic dots) and P·V on MFMA; no __syncthreads.
// Grid (16,48): block = 64 queries of one bh; wave = 16 queries.
// S: A-rows = 16 keys' bf16 log-vecs (quad0 lanes, K-slots 0..7; rest zero),
//    B-rows = this lane's own query log-vec (registers). C gives
//    dot[key=quad*4+reg (+16*kb)][q=qr]. d2 = nq+nk-2dot, w=exp(-dist/8),
//    packed to wave-private w_s rows (A-layout for PV).
// PV: A = w_s rows, B = vt (bh,d,n) read directly from global (L2-resident).
// ---------------------------------------------------------------------------
__global__ __launch_bounds__(256)
void attn_kernel(const unsigned short* __restrict__ lq,
                 const unsigned short* __restrict__ lk,
                 const float* __restrict__ nq, const float* __restrict__ nk,
                 const unsigned short* __restrict__ vt,
                 unsigned short* __restrict__ out)
{
    __shared__ unsigned short w_s[64*72];   // 9 KB, stride 72 (9 granules)

    const int tid  = threadIdx.x;
    const int lane = tid & 63;
    const int wid  = tid >> 6;
    const int qr   = lane & 15;
    const int quad = lane >> 4;
    const int bh   = blockIdx.y;
    const int q0   = blockIdx.x*64 + wid*16;
    const int qrow = (bh << 10) + q0 + qr;
    const int bb   = bh / HQ;
    const int hh   = bh - bb*HQ;

    bf16x8 bq = {};
    if (quad == 0) bq = *(const bf16x8*)(lq + qrow*8);
    const float nqv = nq[qrow];

    f32x4 acc[4] = {};
    float wsum_acc = 0.f;

    const unsigned short* vtg = vt + (bh << 16);   // bh*64*1024
    const unsigned short* lkg = lk + (bh << 13);   // bh*1024*8
    const float*          nkg = nk + (bh << 10);

    for (int c = 0; c < NSEQ; c += 64) {
        float wsum_c = 0.f;
        unsigned wpk[4][2];
        #pragma unroll
        for (int kb = 0; kb < 4; ++kb) {
            bf16x8 ak = {};
            if (quad == 0) ak = *(const bf16x8*)(lkg + (c + kb*16 + qr)*8);
            f32x4 s = {};
            s = __builtin_amdgcn_mfma_f32_16x16x32_bf16(ak, bq, s, 0, 0, 0);
            const float4 nk4 = *(const float4*)(nkg + c + kb*16 + quad*4);
            const float nkv[4] = {nk4.x, nk4.y, nk4.z, nk4.w};
            float w[4];
            #pragma unroll
            for (int r = 0; r < 4; ++r) {
                const float d2 = nqv + nkv[r] - 2.f*s[r];
                const float dist = sqrtf(fmaxf(d2, 1e-12f));
                w[r] = __expf(-0.125f * dist);
                wsum_c += w[r];
            }
            wpk[kb][0] = (unsigned)f2bf(w[0]) | ((unsigned)f2bf(w[1]) << 16);
            wpk[kb][1] = (unsigned)f2bf(w[2]) | ((unsigned)f2bf(w[3]) << 16);
        }
        #pragma unroll
        for (int kb = 0; kb < 4; ++kb)
            *(uint2*)&w_s[(wid*16 + qr)*72 + kb*16 + quad*4] =
                make_uint2(wpk[kb][0], wpk[kb][1]);
        wsum_c += __shfl_xor(wsum_c, 16);
        wsum_c += __shfl_xor(wsum_c, 32);
        wsum_acc += wsum_c;

        #pragma unroll
        for (int s2 = 0; s2 < 2; ++s2) {
            const bf16x8 af = *(const bf16x8*)&w_s[(wid*16 + qr)*72 + s2*32 + quad*8];
            #pragma unroll
            for (int jb = 0; jb < 4; ++jb) {
                const bf16x8 bv = *(const bf16x8*)(vtg + ((jb*16 + qr) << 10) + c + s2*32 + quad*8);
                acc[jb] = __builtin_amdgcn_mfma_f32_16x16x32_bf16(af, bv, acc[jb], 0, 0, 0);
            }
        }
    }

    // epilogue: normalize, store bf16 [b*1024+n][h*64+d] for the O-proj GEMM
    #pragma unroll
    for (int jb = 0; jb < 4; ++jb) {
        #pragma unroll
        for (int r = 0; r < 4; ++r) {
            const int row = quad*4 + r;
            const float wsd = __shfl(wsum_acc, row);
            const int qgl = q0 + row;
            const int d = jb*16 + qr;
            out[((bb << 10) + qgl)*768 + hh*64 + d] = f2bf(acc[jb][r] / wsd);
        }
    }
}

// ---------------------------------------------------------------------------
// KL reduction (unchanged)
// ---------------------------------------------------------------------------
__global__ __launch_bounds__(256)
void kl_partial_kernel(const float* __restrict__ mu0, const float* __restrict__ ls0,
                       const float* __restrict__ mu1, const float* __restrict__ ls1,
                       const float* __restrict__ mu2, const float* __restrict__ ls2,
                       const float* __restrict__ mu3, const float* __restrict__ ls3,
                       double* __restrict__ partials)
{
    const int tid = threadIdx.x;
    double acc = 0.0;
    for (int idx = blockIdx.x*256 + tid; idx < 589824; idx += 256*256) {
        float m, l;
        m = mu0[idx]; l = ls0[idx]; acc += (double)(expf(2.f*l) + m*m - 1.f - 2.f*l);
        m = mu1[idx]; l = ls1[idx]; acc += (double)(expf(2.f*l) + m*m - 1.f - 2.f*l);
        m = mu2[idx]; l = ls2[idx]; acc += (double)(expf(2.f*l) + m*m - 1.f - 2.f*l);
        m = mu3[idx]; l = ls3[idx]; acc += (double)(expf(2.f*l) + m*m - 1.f - 2.f*l);
    }
    __shared__ double sd[256];
    sd[tid] = acc;
    __syncthreads();
    for (int s = 128; s > 0; s >>= 1) {
        if (tid < s) sd[tid] += sd[tid + s];
        __syncthreads();
    }
    if (tid == 0) partials[blockIdx.x] = sd[0];
}

__global__ __launch_bounds__(256)
void kl_final_kernel(const double* __restrict__ partials, float* __restrict__ out_kl)
{
    const int tid = threadIdx.x;
    __shared__ double sd[256];
    sd[tid] = partials[tid];
    __syncthreads();
    for (int s = 128; s > 0; s >>= 1) {
        if (tid < s) sd[tid] += sd[tid + s];
        __syncthreads();
    }
    if (tid == 0) out_kl[0] = (float)(0.5 * sd[0]);
}

// ---------------------------------------------------------------------------
extern "C" void kernel_launch(void* const* d_in, const int* in_sizes, int n_in,
                              void* d_out, int out_size, void* d_ws, size_t ws_size,
                              hipStream_t stream)
{
    const float* x     = (const float*)d_in[0];
    const float* wq    = (const float*)d_in[1];
    const float* wq_ls = (const float*)d_in[2];
    const float* wk    = (const float*)d_in[3];
    const float* wk_ls = (const float*)d_in[4];
    const float* wv    = (const float*)d_in[5];
    const float* wv_ls = (const float*)d_in[6];
    const float* wo    = (const float*)d_in[7];
    const float* wo_ls = (const float*)d_in[8];
    const float* wo_b  = (const float*)d_in[9];
    const float* sq_w  = (const float*)d_in[10];
    const float* sq_b  = (const float*)d_in[11];
    const float* sk_w  = (const float*)d_in[12];
    const float* sk_b  = (const float*)d_in[13];
    float* out = (float*)d_out;

    float* ws = (float*)d_ws;
    float* qb = ws;                                   // 3145728 f
    float* kb = ws + 3145728;                         // 3145728 f
    unsigned short* vt  = (unsigned short*)(ws + 6291456);   // 1572864 f
    unsigned short* xb  = (unsigned short*)(ws + 7864320);   // 1572864 f (re-used as attn bf16 out)
    unsigned short* wf  = (unsigned short*)(ws + 9437184);   // 884736 f
    unsigned short* wob = (unsigned short*)(ws + 10321920);  // 294912 f
    unsigned short* lqb = (unsigned short*)(ws + 10616832);  // 196608 f as bf16
    unsigned short* lkb = (unsigned short*)(ws + 10813440);  // 196608 f as bf16
    float* nqb = ws + 11010048;                       // 49152
    float* nkb = ws + 11059200;                       // 49152
    double* partials = (double*)(ws + 11108352);      // 256 doubles

    const dim3 b256(256);

    convert_kernel<<<dim3(1024, 5), b256, 0, stream>>>(x, wq, wk, wv, wo, xb, wf, wob);
    mfma_gemm<0><<<dim3(18, 32), b256, 0, stream>>>(xb, wf, nullptr, qb, kb, vt, nullptr);
    spd_kernel<<<dim3(1536, 2), b256, 0, stream>>>(qb, kb, sq_w, sq_b, sk_w, sk_b,
                                                   lqb, lkb, nqb, nkb);
    attn_kernel<<<dim3(16, BHD), b256, 0, stream>>>(lqb, lkb, nqb, nkb, vt, xb);
    mfma_gemm<1><<<dim3(6, 32), b256, 0, stream>>>(xb, wob, wo_b, nullptr, nullptr, nullptr, out);
    kl_partial_kernel<<<256, b256, 0, stream>>>(wq, wq_ls, wk, wk_ls, wv, wv_ls,
                                                wo, wo_ls, partials);
    kl_final_kernel<<<1, b256, 0, stream>>>(partials, out + OUT_ELEMS);
}